// Round 1
// baseline (90.301 us; speedup 1.0000x reference)
//
#include <hip/hip_runtime.h>

typedef __attribute__((ext_vector_type(8))) _Float16 f16x8;
typedef __attribute__((ext_vector_type(4))) _Float16 f16x4;
typedef __attribute__((ext_vector_type(4))) float f32x4;

#define NB 16
#define MAXC 256
#define MAXT 4096
#define HID 512
#define NSRC 256
#define TT 64

// gelu(x) ~= x * sigmoid(1.5957691x + 0.0713548x^3)   (tanh-form, |err| ~3e-4)
// folded into exp2: x * rcp(1 + exp2(x * (-2.30220778 - 0.10294336 x^2)))
__device__ __forceinline__ float gelu_fast(float x) {
  float p = x * x;
  float q = __builtin_fmaf(p, -0.10294336f, -2.30220778f);
  float e = __builtin_amdgcn_exp2f(x * q);
  return x * __builtin_amdgcn_rcpf(1.0f + e);
}

// (R x C) fp32 -> (C x R) fp16, one 32x32 tile per block, blockIdx.z = matrix idx
__global__ void transpose_cvt_kernel(const float* __restrict__ src,
                                     _Float16* __restrict__ dst, int R, int C) {
  __shared__ float tile[32][33];
  const float* s = src + (size_t)blockIdx.z * R * C;
  _Float16* d = dst + (size_t)blockIdx.z * R * C;
  int c0 = blockIdx.x * 32, r0 = blockIdx.y * 32;
  int tx = threadIdx.x, ty = threadIdx.y;
  for (int i = ty; i < 32; i += 8)
    tile[i][tx] = s[(size_t)(r0 + i) * C + (c0 + tx)];
  __syncthreads();
  for (int i = ty; i < 32; i += 8)
    d[(size_t)(c0 + i) * R + (r0 + tx)] = (_Float16)tile[tx][i];
}

// One workgroup = one (batch, 64-wide time tile). 8 waves.
// GEMM1: h[512 x 64] = W1t(512x256) @ x(256x64), +bias, gelu -> Hs (fp16, 2 chunks of 256)
// GEMM2: out[256 x 64] = W2t(256x512) @ h, +bias, tmask
__global__ __launch_bounds__(512, 4)
void fused_sess_proj_kernel(const float* __restrict__ x,
                            const int* __restrict__ sess_ids,
                            const int* __restrict__ seq_lens,
                            const _Float16* __restrict__ W1t,   // [8][HID][MAXC]
                            const float* __restrict__ b_sess,   // [8][HID]
                            const _Float16* __restrict__ W2t,   // [NSRC][HID]
                            const float* __restrict__ b2,       // [NSRC]
                            float* __restrict__ out) {
  int wg = blockIdx.x;
  int b = wg >> 6;
  int t0 = (wg & 63) * TT;
  int seqlen = seq_lens[b];
  int tid = threadIdx.x;

  if (t0 >= seqlen) {  // fully masked tile: just write zeros (d_out is poisoned)
    int row = tid >> 1;
    int part = tid & 1;
    float* po = out + ((size_t)b * NSRC + row) * MAXT + t0 + part * 32;
    f32x4 z = {0.f, 0.f, 0.f, 0.f};
    #pragma unroll
    for (int i = 0; i < 8; ++i) *(f32x4*)(po + i * 4) = z;
    return;
  }

  // swizzled [t][c] / [t][hh] layouts: elem idx = t*256 + (col ^ ((t&7)<<3))
  __shared__ _Float16 Xs[TT * MAXC];  // 32 KB
  __shared__ _Float16 Hs[TT * 256];   // 32 KB (one 256-row h-chunk at a time)

  // ---- stage X^T tile as fp16 (lane-per-channel; conflict-free LDS writes) ----
  {
    int c = tid & 255;
    int th = tid >> 8;  // 0..1 halves of the 64 times
    const float* xp = x + ((size_t)b * MAXC + c) * MAXT + t0 + th * 32;
    #pragma unroll
    for (int i = 0; i < 8; ++i) {
      f32x4 v = *(const f32x4*)(xp + i * 4);
      #pragma unroll
      for (int k = 0; k < 4; ++k) {
        int t = th * 32 + i * 4 + k;
        Xs[t * 256 + (c ^ ((t & 7) << 3))] = (_Float16)v[k];
      }
    }
  }
  __syncthreads();

  int lane = tid & 63;
  int w = tid >> 6;    // wave 0..7
  int lg = lane >> 4;  // k-group / row-group
  int lr = lane & 15;  // m-row (A) / n-col (B,D)
  int sid = sess_ids[b];
  const _Float16* W1s = W1t + (size_t)sid * HID * MAXC;

  // GEMM2 accumulators persist across both h-chunks; init with b2
  f32x4 acc2[2][4];
  #pragma unroll
  for (int mi = 0; mi < 2; ++mi) {
    f32x4 bv = *(const f32x4*)(b2 + w * 32 + mi * 16 + lg * 4);
    #pragma unroll
    for (int ni = 0; ni < 4; ++ni) acc2[mi][ni] = bv;
  }

  #pragma unroll
  for (int ch = 0; ch < 2; ++ch) {
    // ---- GEMM1: this wave owns h rows [ch*256 + w*32, +32) ----
    f32x4 acc1[2][4];
    #pragma unroll
    for (int mi = 0; mi < 2; ++mi) {
      f32x4 bv = *(const f32x4*)(b_sess + sid * HID + ch * 256 + w * 32 + mi * 16 + lg * 4);
      #pragma unroll
      for (int ni = 0; ni < 4; ++ni) acc1[mi][ni] = bv;
    }
    #pragma unroll
    for (int ks = 0; ks < 8; ++ks) {
      int k0 = ks * 32;
      f16x8 af[2], bf[4];
      #pragma unroll
      for (int mi = 0; mi < 2; ++mi)
        af[mi] = *(const f16x8*)(W1s +
            (size_t)(ch * 256 + w * 32 + mi * 16 + lr) * MAXC + k0 + lg * 8);
      #pragma unroll
      for (int ni = 0; ni < 4; ++ni) {
        int t = ni * 16 + lr;
        bf[ni] = *(const f16x8*)(&Xs[t * 256 + ((k0 + lg * 8) ^ ((t & 7) << 3))]);
      }
      #pragma unroll
      for (int mi = 0; mi < 2; ++mi)
        #pragma unroll
        for (int ni = 0; ni < 4; ++ni)
          acc1[mi][ni] = __builtin_amdgcn_mfma_f32_16x16x32_f16(af[mi], bf[ni], acc1[mi][ni], 0, 0, 0);
    }
    // ---- gelu -> Hs (packed 8B writes, swizzled) ----
    #pragma unroll
    for (int mi = 0; mi < 2; ++mi) {
      int hh = w * 32 + mi * 16 + lg * 4;
      #pragma unroll
      for (int ni = 0; ni < 4; ++ni) {
        int t = ni * 16 + lr;
        f16x4 g;
        #pragma unroll
        for (int r = 0; r < 4; ++r) g[r] = (_Float16)gelu_fast(acc1[mi][ni][r]);
        *(f16x4*)(&Hs[t * 256 + (hh ^ ((t & 7) << 3))]) = g;
      }
    }
    __syncthreads();
    // ---- GEMM2 partial accumulate over k = ch*256 .. ch*256+255 ----
    #pragma unroll
    for (int ks = 0; ks < 8; ++ks) {
      int k0 = ks * 32;
      f16x8 af[2], bf[4];
      #pragma unroll
      for (int mi = 0; mi < 2; ++mi)
        af[mi] = *(const f16x8*)(W2t +
            (size_t)(w * 32 + mi * 16 + lr) * HID + ch * 256 + k0 + lg * 8);
      #pragma unroll
      for (int ni = 0; ni < 4; ++ni) {
        int t = ni * 16 + lr;
        bf[ni] = *(const f16x8*)(&Hs[t * 256 + ((k0 + lg * 8) ^ ((t & 7) << 3))]);
      }
      #pragma unroll
      for (int mi = 0; mi < 2; ++mi)
        #pragma unroll
        for (int ni = 0; ni < 4; ++ni)
          acc2[mi][ni] = __builtin_amdgcn_mfma_f32_16x16x32_f16(af[mi], bf[ni], acc2[mi][ni], 0, 0, 0);
    }
    __syncthreads();  // protect Hs before next chunk's overwrite
  }

  // ---- epilogue: time mask + fp32 store ----
  #pragma unroll
  for (int mi = 0; mi < 2; ++mi) {
    int s0 = w * 32 + mi * 16 + lg * 4;
    #pragma unroll
    for (int ni = 0; ni < 4; ++ni) {
      int t = t0 + ni * 16 + lr;
      float m = (t < seqlen) ? 1.0f : 0.0f;
      #pragma unroll
      for (int r = 0; r < 4; ++r)
        out[((size_t)b * NSRC + s0 + r) * MAXT + t] = acc2[mi][ni][r] * m;
    }
  }
}

extern "C" void kernel_launch(void* const* d_in, const int* in_sizes, int n_in,
                              void* d_out, int out_size, void* d_ws, size_t ws_size,
                              hipStream_t stream) {
  const float* x      = (const float*)d_in[0];
  const int* sess     = (const int*)d_in[1];
  // d_in[2] = channel_counts: unused (x is already zero-padded past true channels)
  const int* seq      = (const int*)d_in[3];
  const float* W_sess = (const float*)d_in[4];
  const float* b_sess = (const float*)d_in[5];
  const float* W2     = (const float*)d_in[6];
  const float* b2     = (const float*)d_in[7];
  float* out = (float*)d_out;

  _Float16* W1t = (_Float16*)d_ws;                               // [8][512][256]
  _Float16* W2t = (_Float16*)((char*)d_ws + (size_t)8 * HID * MAXC * sizeof(_Float16));

  dim3 tb(32, 8);
  // W_sess: per session (256 x 512) -> (512 x 256) fp16
  transpose_cvt_kernel<<<dim3(HID / 32, MAXC / 32, 8), tb, 0, stream>>>(W_sess, W1t, MAXC, HID);
  // W2: (512 x 256) -> (256 x 512) fp16
  transpose_cvt_kernel<<<dim3(NSRC / 32, HID / 32, 1), tb, 0, stream>>>(W2, W2t, HID, NSRC);

  fused_sess_proj_kernel<<<dim3(NB * (MAXT / TT)), dim3(512), 0, stream>>>(
      x, sess, seq, W1t, b_sess, W2t, b2, out);
}